// Round 5
// baseline (1780.106 us; speedup 1.0000x reference)
//
#include <hip/hip_runtime.h>
#include <math.h>

// WaveNet forward, round 5: latency attack.
// - XCD-affinity swizzle: 1-D grid, xcd = bid&7 (assumes round-robin dispatch),
//   each XCD owns a contiguous tile range, stable across ALL layer launches and
//   the head -> h ping-pong reads and chunk RMW stay in the writer XCD's L2.
// - G (gated) lives in X's tap-0 columns after conv -> LDS 33.8 KB.
// - chunk RMW operands prefetched at kernel start; conv A-frags loaded 4-wide.
// Layouts unchanged from round 4 (h f16 [n][t][c]; chunk f16 frag-linear).

#define NB 4
#define WLEN 16384
#define C 128
#define S 256
#define NLAYERS 30
#define TT 64
#define NTB (WLEN / TT)   // 256 tiles per sample
#define XROW 264          // X row stride (f16): 256 + 8 pad

typedef _Float16 half8 __attribute__((ext_vector_type(8)));
typedef _Float16 half4 __attribute__((ext_vector_type(4)));
typedef float floatx4 __attribute__((ext_vector_type(4)));

__device__ __forceinline__ float sigmoidf_(float v) {
    return 1.0f / (1.0f + __expf(-v));
}

// ---------------- weight packing (unchanged from round 4) ----------------
__global__ void prep_kernel(const float* __restrict__ conv_w,
                            const float* __restrict__ res_w,
                            const float* __restrict__ skip_w,
                            const float* __restrict__ a_w,
                            const float* __restrict__ b_w,
                            const float* __restrict__ conv_b,
                            const float* __restrict__ skip_b,
                            _Float16* __restrict__ cw,
                            _Float16* __restrict__ rsw,
                            _Float16* __restrict__ skw,
                            _Float16* __restrict__ aw,
                            _Float16* __restrict__ bw,
                            float* __restrict__ cbp,
                            float* __restrict__ ssum) {
    const int ncw = NLAYERS * 256 * 256;
    const int nrs = NLAYERS * 128 * 128;
    const int nsk = NLAYERS * 256 * 128;
    const int nab = 256 * 256;
    const int ncb = NLAYERS * 256;
    const int total = ncw + nrs + nsk + nab + nab + ncb + 256;
    for (int idx = blockIdx.x * blockDim.x + threadIdx.x; idx < total;
         idx += gridDim.x * blockDim.x) {
        int i = idx;
        if (i < ncw) {
            int j = i & 7, lane = (i >> 3) & 63, rest = i >> 9;
            int ks = rest & 7; rest >>= 3;
            int mt = rest & 15; int l = rest >> 4;
            int mp = mt * 16 + (lane & 15);
            int orow = (mp >> 1) + (mp & 1) * 128;
            int k = ks * 32 + (lane >> 4) * 8 + j;
            int tap = k >> 7, c = k & 127;
            cw[i] = (_Float16)conv_w[(((size_t)l * 256 + orow) * 128 + c) * 2 + tap];
        } else if (i < ncw + nrs) {
            i -= ncw;
            int j = i & 7, lane = (i >> 3) & 63, rest = i >> 9;
            int ks = rest & 3; rest >>= 2;
            int mt = rest & 7; int l = rest >> 3;
            int m = mt * 16 + (lane & 15);
            int k = ks * 32 + (lane >> 4) * 8 + j;
            rsw[i] = (_Float16)res_w[((size_t)l * 128 + m) * 128 + k];
        } else if (i < ncw + nrs + nsk) {
            i -= ncw + nrs;
            int j = i & 7, lane = (i >> 3) & 63, rest = i >> 9;
            int ks = rest & 3; rest >>= 2;
            int mt = rest & 15; int l = rest >> 4;
            int m = mt * 16 + (lane & 15);
            int k = ks * 32 + (lane >> 4) * 8 + j;
            skw[i] = (_Float16)skip_w[((size_t)l * 256 + m) * 128 + k];
        } else if (i < ncw + nrs + nsk + nab) {
            i -= ncw + nrs + nsk;
            int j = i & 7, lane = (i >> 3) & 63, rest = i >> 9;
            int ks = rest & 7; int mt = rest >> 3;
            aw[i] = (_Float16)a_w[(mt * 16 + (lane & 15)) * 256 + ks * 32 + (lane >> 4) * 8 + j];
        } else if (i < ncw + nrs + nsk + 2 * nab) {
            i -= ncw + nrs + nsk + nab;
            int j = i & 7, lane = (i >> 3) & 63, rest = i >> 9;
            int ks = rest & 7; int mt = rest >> 3;
            bw[i] = (_Float16)b_w[(mt * 16 + (lane & 15)) * 256 + ks * 32 + (lane >> 4) * 8 + j];
        } else if (i < ncw + nrs + nsk + 2 * nab + ncb) {
            i -= ncw + nrs + nsk + 2 * nab;
            int mp = i & 255; int l = i >> 8;
            cbp[i] = conv_b[l * 256 + (mp >> 1) + (mp & 1) * 128];
        } else {
            i -= ncw + nrs + nsk + 2 * nab + ncb;
            float s = 0.f;
            for (int l = 0; l < NLAYERS; ++l) s += skip_b[l * 256 + i];
            ssum[i] = s;
        }
    }
}

// ---------------- front: h0 (f16, [n][t][c]) ----------------
__global__ void front_kernel(const float* __restrict__ x,
                             const float* __restrict__ w_shift,
                             const float* __restrict__ b_shift,
                             _Float16* __restrict__ h) {
    const int n = blockIdx.y;
    const int t = blockIdx.x * 256 + threadIdx.x;
    float x1 = (t >= 1) ? x[n * WLEN + t - 1] : 0.0f;
    float x2 = (t >= 2) ? x[n * WLEN + t - 2] : 0.0f;
    _Float16* hq = h + ((size_t)n * WLEN + t) * 128;
    #pragma unroll
    for (int c0 = 0; c0 < 128; c0 += 8) {
        half8 v;
        #pragma unroll
        for (int j = 0; j < 8; ++j) {
            int c = c0 + j;
            v[j] = (_Float16)fmaf(w_shift[2 * c], x2,
                                  fmaf(w_shift[2 * c + 1], x1, b_shift[c]));
        }
        *(half8*)&hq[c0] = v;
    }
}

// XCD-affinity tile mapping: assumes round-robin blockIdx->XCD dispatch.
__device__ __forceinline__ void tile_map(int bid, int& n, int& tb) {
    int xcd = bid & 7;
    int idx = bid >> 3;
    int g = xcd * 128 + idx;   // contiguous 128-tile range per XCD
    n = g >> 8;
    tb = g & 255;
}

// ---------------- one residual layer (conv + GLU + skip-RMW + res) ----------------
template <bool FIRST>
__global__ __launch_bounds__(256, 3) void layer_kernel(
    const _Float16* __restrict__ h_in, _Float16* __restrict__ h_out,
    _Float16* __restrict__ chunk,
    const _Float16* __restrict__ cw, const float* __restrict__ cb,
    const _Float16* __restrict__ rsw, const float* __restrict__ rb,
    const _Float16* __restrict__ skw, const float* __restrict__ ssum, int d) {
    __shared__ _Float16 X[TT * XROW];  // 33792 B; cols 0..127 become G after conv
    int n, tb;
    tile_map(blockIdx.x, n, tb);
    const int t0 = tb * TT;
    const int tid = threadIdx.x;
    const int wave = __builtin_amdgcn_readfirstlane(tid >> 6);
    const int lane = tid & 63, q = lane >> 4, ml = lane & 15;

    // ---- prefetch chunk RMW operands (independent; ~L2/L3 latency hidden)
    _Float16* cp = chunk + ((size_t)n * NTB + tb) * 16384;
    half4 cpre[4][4];
    if (!FIRST) {
        #pragma unroll
        for (int mt = 0; mt < 4; ++mt)
            #pragma unroll
            for (int nt = 0; nt < 4; ++nt)
                cpre[mt][nt] = *(const half4*)
                    &cp[(size_t)((((wave * 4 + mt) * 4) + nt) * 64 + lane) * 4];
    }

    // ---- stage both taps: contiguous 16B row-segment copies
    const _Float16* hn = h_in + (size_t)n * WLEN * 128;
    #pragma unroll
    for (int it = 0; it < 8; ++it) {
        int idx = it * 256 + tid;        // 0..2047
        int seg = idx & 15;
        int rowc = (idx >> 4) & 63;
        int tap = idx >> 10;             // 0: t-d, 1: t
        int src_t = t0 + rowc - (tap ? 0 : d);
        half8 v = (half8)(_Float16)0.0f;
        if (src_t >= 0)
            v = *(const half8*)&hn[(size_t)src_t * 128 + seg * 8];
        *(half8*)&X[rowc * XROW + tap * 128 + seg * 8] = v;
    }
    __syncthreads();

    // ---- conv GEMM (interleaved rows): D[m'][t], K=256
    floatx4 acc[4][4];
    #pragma unroll
    for (int mt = 0; mt < 4; ++mt)
        #pragma unroll
        for (int r = 0; r < 4; ++r) {
            float bias = cb[64 * wave + mt * 16 + q * 4 + r];
            #pragma unroll
            for (int nt = 0; nt < 4; ++nt) acc[mt][nt][r] = bias;
        }
    for (int ks = 0; ks < 8; ++ks) {
        // all 4 A-frag global loads issued together
        half8 a0 = *(const half8*)&cw[((((4 * wave + 0) * 8) + ks) * 64 + lane) * 8];
        half8 a1 = *(const half8*)&cw[((((4 * wave + 1) * 8) + ks) * 64 + lane) * 8];
        half8 a2 = *(const half8*)&cw[((((4 * wave + 2) * 8) + ks) * 64 + lane) * 8];
        half8 a3 = *(const half8*)&cw[((((4 * wave + 3) * 8) + ks) * 64 + lane) * 8];
        half8 b[4];
        #pragma unroll
        for (int nt = 0; nt < 4; ++nt)
            b[nt] = *(const half8*)&X[(nt * 16 + ml) * XROW + ks * 32 + q * 8];
        #pragma unroll
        for (int nt = 0; nt < 4; ++nt)
            acc[0][nt] = __builtin_amdgcn_mfma_f32_16x16x32_f16(a0, b[nt], acc[0][nt], 0, 0, 0);
        #pragma unroll
        for (int nt = 0; nt < 4; ++nt)
            acc[1][nt] = __builtin_amdgcn_mfma_f32_16x16x32_f16(a1, b[nt], acc[1][nt], 0, 0, 0);
        #pragma unroll
        for (int nt = 0; nt < 4; ++nt)
            acc[2][nt] = __builtin_amdgcn_mfma_f32_16x16x32_f16(a2, b[nt], acc[2][nt], 0, 0, 0);
        #pragma unroll
        for (int nt = 0; nt < 4; ++nt)
            acc[3][nt] = __builtin_amdgcn_mfma_f32_16x16x32_f16(a3, b[nt], acc[3][nt], 0, 0, 0);
    }
    __syncthreads();  // every wave done reading X before tap-0 cols become G

    // ---- GLU in registers -> G = X cols 0..127 (tap-1 cols preserved for residual)
    #pragma unroll
    for (int mt = 0; mt < 4; ++mt)
        #pragma unroll
        for (int nt = 0; nt < 4; ++nt) {
            float g0 = acc[mt][nt][0] * sigmoidf_(acc[mt][nt][1]);
            float g1 = acc[mt][nt][2] * sigmoidf_(acc[mt][nt][3]);
            _Float16 p[2] = {(_Float16)g0, (_Float16)g1};
            *(uint32_t*)&X[(nt * 16 + ml) * XROW + 32 * wave + mt * 8 + 2 * q] = *(uint32_t*)p;
        }
    __syncthreads();

    // ---- skip GEMM (M=256) + f16 frag-linear RMW using prefetched cpre
    {
        floatx4 sacc[4][4];
        #pragma unroll
        for (int mt = 0; mt < 4; ++mt)
            #pragma unroll
            for (int r = 0; r < 4; ++r) {
                float bias = FIRST ? ssum[64 * wave + mt * 16 + q * 4 + r] : 0.0f;
                #pragma unroll
                for (int nt = 0; nt < 4; ++nt) sacc[mt][nt][r] = bias;
            }
        #pragma unroll
        for (int ks = 0; ks < 4; ++ks) {
            half8 a0 = *(const half8*)&skw[((((4 * wave + 0) * 4) + ks) * 64 + lane) * 8];
            half8 a1 = *(const half8*)&skw[((((4 * wave + 1) * 4) + ks) * 64 + lane) * 8];
            half8 a2 = *(const half8*)&skw[((((4 * wave + 2) * 4) + ks) * 64 + lane) * 8];
            half8 a3 = *(const half8*)&skw[((((4 * wave + 3) * 4) + ks) * 64 + lane) * 8];
            half8 b[4];
            #pragma unroll
            for (int nt = 0; nt < 4; ++nt)
                b[nt] = *(const half8*)&X[(nt * 16 + ml) * XROW + ks * 32 + q * 8];
            #pragma unroll
            for (int nt = 0; nt < 4; ++nt)
                sacc[0][nt] = __builtin_amdgcn_mfma_f32_16x16x32_f16(a0, b[nt], sacc[0][nt], 0, 0, 0);
            #pragma unroll
            for (int nt = 0; nt < 4; ++nt)
                sacc[1][nt] = __builtin_amdgcn_mfma_f32_16x16x32_f16(a1, b[nt], sacc[1][nt], 0, 0, 0);
            #pragma unroll
            for (int nt = 0; nt < 4; ++nt)
                sacc[2][nt] = __builtin_amdgcn_mfma_f32_16x16x32_f16(a2, b[nt], sacc[2][nt], 0, 0, 0);
            #pragma unroll
            for (int nt = 0; nt < 4; ++nt)
                sacc[3][nt] = __builtin_amdgcn_mfma_f32_16x16x32_f16(a3, b[nt], sacc[3][nt], 0, 0, 0);
        }
        #pragma unroll
        for (int mt = 0; mt < 4; ++mt)
            #pragma unroll
            for (int nt = 0; nt < 4; ++nt) {
                size_t o = (size_t)((((wave * 4 + mt) * 4) + nt) * 64 + lane) * 4;
                half4 w;
                if (FIRST) {
                    #pragma unroll
                    for (int r = 0; r < 4; ++r) w[r] = (_Float16)sacc[mt][nt][r];
                } else {
                    #pragma unroll
                    for (int r = 0; r < 4; ++r)
                        w[r] = (_Float16)(sacc[mt][nt][r] + (float)cpre[mt][nt][r]);
                }
                *(half4*)&cp[o] = w;
            }
    }

    // ---- res GEMM (M=128) + residual add from preserved tap-1 cols
    {
        floatx4 racc[2][4];
        #pragma unroll
        for (int mt = 0; mt < 2; ++mt)
            #pragma unroll
            for (int r = 0; r < 4; ++r) {
                float bias = rb[32 * wave + mt * 16 + q * 4 + r];
                #pragma unroll
                for (int nt = 0; nt < 4; ++nt) racc[mt][nt][r] = bias;
            }
        #pragma unroll
        for (int ks = 0; ks < 4; ++ks) {
            half8 a0 = *(const half8*)&rsw[((((2 * wave + 0) * 4) + ks) * 64 + lane) * 8];
            half8 a1 = *(const half8*)&rsw[((((2 * wave + 1) * 4) + ks) * 64 + lane) * 8];
            half8 b[4];
            #pragma unroll
            for (int nt = 0; nt < 4; ++nt)
                b[nt] = *(const half8*)&X[(nt * 16 + ml) * XROW + ks * 32 + q * 8];
            #pragma unroll
            for (int nt = 0; nt < 4; ++nt)
                racc[0][nt] = __builtin_amdgcn_mfma_f32_16x16x32_f16(a0, b[nt], racc[0][nt], 0, 0, 0);
            #pragma unroll
            for (int nt = 0; nt < 4; ++nt)
                racc[1][nt] = __builtin_amdgcn_mfma_f32_16x16x32_f16(a1, b[nt], racc[1][nt], 0, 0, 0);
        }
        _Float16* ho = h_out + (size_t)n * WLEN * 128;
        #pragma unroll
        for (int mt = 0; mt < 2; ++mt)
            #pragma unroll
            for (int nt = 0; nt < 4; ++nt) {
                int tt = nt * 16 + ml;
                int c = 32 * wave + mt * 16 + q * 4;
                half4 hv = *(const half4*)&X[tt * XROW + 128 + c];
                half4 o;
                #pragma unroll
                for (int r = 0; r < 4; ++r)
                    o[r] = (_Float16)(racc[mt][nt][r] + (float)hv[r]);
                *(half4*)&ho[(size_t)(t0 + tt) * 128 + c] = o;
            }
    }
}

// ---------------- head: chunk -> relu -> a_w -> relu -> b_w -> logits ----------------
__global__ __launch_bounds__(256, 4) void head_kernel(
    float* __restrict__ out, const _Float16* __restrict__ chunk,
    const _Float16* __restrict__ aw, const float* __restrict__ ab,
    const _Float16* __restrict__ bw, const float* __restrict__ bb) {
    __shared__ _Float16 X[TT * XROW];
    int n, tb;
    tile_map(blockIdx.x, n, tb);
    const int t0 = tb * TT;
    const int tid = threadIdx.x;
    const int wave = __builtin_amdgcn_readfirstlane(tid >> 6);
    const int lane = tid & 63, q = lane >> 4, ml = lane & 15;

    {
        const _Float16* cp = chunk + ((size_t)n * NTB + tb) * 16384;
        #pragma unroll
        for (int mt = 0; mt < 4; ++mt)
            #pragma unroll
            for (int nt = 0; nt < 4; ++nt) {
                size_t o = (size_t)((((wave * 4 + mt) * 4) + nt) * 64 + lane) * 4;
                half4 v = *(const half4*)&cp[o];
                half4 z;
                #pragma unroll
                for (int r = 0; r < 4; ++r)
                    z[r] = (_Float16)fmaxf((float)v[r], 0.0f);
                *(half4*)&X[(nt * 16 + ml) * XROW + 64 * wave + mt * 16 + q * 4] = z;
            }
    }
    __syncthreads();

    floatx4 acc[4][4];
    #pragma unroll
    for (int mt = 0; mt < 4; ++mt)
        #pragma unroll
        for (int r = 0; r < 4; ++r) {
            float bias = ab[64 * wave + mt * 16 + q * 4 + r];
            #pragma unroll
            for (int nt = 0; nt < 4; ++nt) acc[mt][nt][r] = bias;
        }
    for (int ks = 0; ks < 8; ++ks) {
        half8 b[4];
        #pragma unroll
        for (int nt = 0; nt < 4; ++nt)
            b[nt] = *(const half8*)&X[(nt * 16 + ml) * XROW + ks * 32 + q * 8];
        #pragma unroll
        for (int mt = 0; mt < 4; ++mt) {
            half8 a = *(const half8*)&aw[((((4 * wave + mt) * 8) + ks) * 64 + lane) * 8];
            #pragma unroll
            for (int nt = 0; nt < 4; ++nt)
                acc[mt][nt] = __builtin_amdgcn_mfma_f32_16x16x32_f16(a, b[nt], acc[mt][nt], 0, 0, 0);
        }
    }
    __syncthreads();
    #pragma unroll
    for (int mt = 0; mt < 4; ++mt)
        #pragma unroll
        for (int nt = 0; nt < 4; ++nt) {
            half4 z;
            #pragma unroll
            for (int r = 0; r < 4; ++r)
                z[r] = (_Float16)fmaxf(acc[mt][nt][r], 0.0f);
            *(half4*)&X[(nt * 16 + ml) * XROW + 64 * wave + mt * 16 + q * 4] = z;
        }
    __syncthreads();

    #pragma unroll
    for (int mt = 0; mt < 4; ++mt)
        #pragma unroll
        for (int r = 0; r < 4; ++r) {
            float bias = bb[64 * wave + mt * 16 + q * 4 + r];
            #pragma unroll
            for (int nt = 0; nt < 4; ++nt) acc[mt][nt][r] = bias;
        }
    for (int ks = 0; ks < 8; ++ks) {
        half8 b[4];
        #pragma unroll
        for (int nt = 0; nt < 4; ++nt)
            b[nt] = *(const half8*)&X[(nt * 16 + ml) * XROW + ks * 32 + q * 8];
        #pragma unroll
        for (int mt = 0; mt < 4; ++mt) {
            half8 a = *(const half8*)&bw[((((4 * wave + mt) * 8) + ks) * 64 + lane) * 8];
            #pragma unroll
            for (int nt = 0; nt < 4; ++nt)
                acc[mt][nt] = __builtin_amdgcn_mfma_f32_16x16x32_f16(a, b[nt], acc[mt][nt], 0, 0, 0);
        }
    }
    float* on = out + (size_t)n * S * WLEN;
    #pragma unroll
    for (int mt = 0; mt < 4; ++mt)
        #pragma unroll
        for (int nt = 0; nt < 4; ++nt)
            #pragma unroll
            for (int r = 0; r < 4; ++r) {
                int o = 64 * wave + mt * 16 + q * 4 + r;
                int tt = t0 + nt * 16 + ml;
                on[(size_t)o * WLEN + tt] = acc[mt][nt][r];
            }
}

extern "C" void kernel_launch(void* const* d_in, const int* in_sizes, int n_in,
                              void* d_out, int out_size, void* d_ws, size_t ws_size,
                              hipStream_t stream) {
    (void)in_sizes; (void)n_in; (void)out_size; (void)ws_size;
    const float* x       = (const float*)d_in[0];
    const float* w_shift = (const float*)d_in[1];
    const float* b_shift = (const float*)d_in[2];
    const float* conv_w  = (const float*)d_in[3];
    const float* conv_b  = (const float*)d_in[4];
    const float* res_w   = (const float*)d_in[5];
    const float* res_b   = (const float*)d_in[6];
    const float* skip_w  = (const float*)d_in[7];
    const float* skip_b  = (const float*)d_in[8];
    const float* a_w     = (const float*)d_in[9];
    const float* a_b     = (const float*)d_in[10];
    const float* b_w     = (const float*)d_in[11];
    const float* b_b     = (const float*)d_in[12];
    float* out = (float*)d_out;

    char* ws = (char*)d_ws;
    size_t off = 0;
    _Float16* hA    = (_Float16*)(ws + off); off += (size_t)NB * WLEN * 128 * 2;
    _Float16* hB    = (_Float16*)(ws + off); off += (size_t)NB * WLEN * 128 * 2;
    _Float16* chunk = (_Float16*)(ws + off); off += (size_t)NB * NTB * 16384 * 2;
    _Float16* cw  = (_Float16*)(ws + off); off += (size_t)NLAYERS * 256 * 256 * 2;
    _Float16* rsw = (_Float16*)(ws + off); off += (size_t)NLAYERS * 128 * 128 * 2;
    _Float16* skw = (_Float16*)(ws + off); off += (size_t)NLAYERS * 256 * 128 * 2;
    _Float16* aw  = (_Float16*)(ws + off); off += 256 * 256 * 2;
    _Float16* bw  = (_Float16*)(ws + off); off += 256 * 256 * 2;
    float* cbp  = (float*)(ws + off); off += (size_t)NLAYERS * 256 * 4;
    float* ssum = (float*)(ws + off); off += 256 * 4;

    prep_kernel<<<512, 256, 0, stream>>>(conv_w, res_w, skip_w, a_w, b_w,
                                         conv_b, skip_b,
                                         cw, rsw, skw, aw, bw, cbp, ssum);
    front_kernel<<<dim3(WLEN / 256, NB), 256, 0, stream>>>(x, w_shift, b_shift, hA);

    _Float16* hin = hA;
    _Float16* hout = hB;
    for (int l = 0; l < NLAYERS; ++l) {
        int dil = 1 << (l % 10);
        const _Float16* cwp = cw + (size_t)l * 65536;
        const _Float16* rsp = rsw + (size_t)l * 16384;
        const _Float16* skp = skw + (size_t)l * 32768;
        if (l == 0)
            layer_kernel<true><<<1024, 256, 0, stream>>>(
                hin, hout, chunk, cwp, cbp + l * 256,
                rsp, res_b + l * 128, skp, ssum, dil);
        else
            layer_kernel<false><<<1024, 256, 0, stream>>>(
                hin, hout, chunk, cwp, cbp + l * 256,
                rsp, res_b + l * 128, skp, ssum, dil);
        _Float16* tmp = hin; hin = hout; hout = tmp;
    }

    head_kernel<<<1024, 256, 0, stream>>>(out, chunk, aw, a_b, bw, b_b);
}